// Round 1
// 124.639 us; speedup vs baseline: 1.1019x; 1.1019x over previous
//
#include <hip/hip_runtime.h>
#include <math.h>

// Problem constants (from reference)
constexpr int VOCAB = 100000;
constexpr int DIM   = 128;
constexpr int B     = 16384;
constexpr int K     = 10;
constexpr int BPB   = 8;           // batch elements per block (256 thr = 8 x 32-lane groups)
constexpr int GRID  = B / BPB;     // 2048 blocks -> exactly 8 blocks/CU on 256 CUs

// Kernel 1: per-block partial sum of log-sigmoid losses -> d_ws[blockIdx.x].
// 32 lanes per batch element; each lane loads float4 (4 dims) -> 32*4 = 128 = DIM.
// No atomics, no dependency on the output buffer.
__global__ __launch_bounds__(256) void skipgram_partial_kernel(
    const int*   __restrict__ center_id,
    const int*   __restrict__ pos_id,
    const int*   __restrict__ neg_ids,
    const float* __restrict__ W_in,
    const float* __restrict__ W_out,
    float*       __restrict__ partial)
{
    const int tid    = threadIdx.x;
    const int lane32 = tid & 31;   // dim-group index (0..31)
    const int sub    = tid >> 5;   // batch element within block (0..7)
    const int b      = blockIdx.x * BPB + sub;

    // Issue all index loads up front so the 12 gather addresses resolve in one
    // memory round-trip (compiler can overlap all index loads).
    const int cid = center_id[b];
    const int pid = pos_id[b];
    int nid[K];
#pragma unroll
    for (int k = 0; k < K; ++k) nid[k] = neg_ids[b * K + k];

    const float4 c = ((const float4*)(W_in  + (size_t)cid * DIM))[lane32];
    const float4 p = ((const float4*)(W_out + (size_t)pid * DIM))[lane32];

    // Sum the 10 negative rows first: neg contribution is
    // log_sigmoid(-dot(center, sum_k neg_k))  (sum over k happens before sigmoid)
    float4 ns = make_float4(0.f, 0.f, 0.f, 0.f);
#pragma unroll
    for (int k = 0; k < K; ++k) {
        const float4 n = ((const float4*)(W_out + (size_t)nid[k] * DIM))[lane32];
        ns.x += n.x; ns.y += n.y; ns.z += n.z; ns.w += n.w;
    }

    float pos_partial = c.x * p.x  + c.y * p.y  + c.z * p.z  + c.w * p.w;
    float neg_partial = c.x * ns.x + c.y * ns.y + c.z * ns.z + c.w * ns.w;

    // Reduce across the 32 lanes sharing this batch element.
    // xor masks <= 16 stay within each 32-lane half of the 64-lane wave.
#pragma unroll
    for (int m = 16; m >= 1; m >>= 1) {
        pos_partial += __shfl_xor(pos_partial, m, 64);
        neg_partial += __shfl_xor(neg_partial, m, 64);
    }

    __shared__ float blocksum[BPB];
    if (lane32 == 0) {
        const float ps  = pos_partial;
        const float nsc = neg_partial;
        // stable log_sigmoid(x) = min(x,0) - log1p(exp(-|x|))
        const float lp = fminf(ps,   0.f) - log1pf(expf(-fabsf(ps)));
        const float ln = fminf(-nsc, 0.f) - log1pf(expf(-fabsf(nsc)));
        blocksum[sub] = lp + ln;
    }
    __syncthreads();

    if (tid == 0) {
        float s = 0.f;
#pragma unroll
        for (int i = 0; i < BPB; ++i) s += blocksum[i];
        partial[blockIdx.x] = s;
    }
}

// Kernel 2: reduce GRID=2048 partials -> out[0] = -(total loss).
// One block of 256 threads: 2 x float4 per thread covers 2048 floats.
__global__ __launch_bounds__(256) void skipgram_reduce_kernel(
    const float* __restrict__ partial,
    float*       __restrict__ out)
{
    const int tid = threadIdx.x;
    const float4* p4 = (const float4*)partial;   // 2048 floats = 512 float4

    float s = 0.f;
#pragma unroll
    for (int i = 0; i < 2; ++i) {
        const float4 v = p4[tid + i * 256];      // indices 0..511
        s += v.x + v.y + v.z + v.w;
    }

    // Full 64-lane wave reduction.
#pragma unroll
    for (int m = 32; m >= 1; m >>= 1) s += __shfl_xor(s, m, 64);

    __shared__ float wsum[4];
    if ((tid & 63) == 0) wsum[tid >> 6] = s;
    __syncthreads();

    if (tid == 0) out[0] = -(wsum[0] + wsum[1] + wsum[2] + wsum[3]);
}

extern "C" void kernel_launch(void* const* d_in, const int* in_sizes, int n_in,
                              void* d_out, int out_size, void* d_ws, size_t ws_size,
                              hipStream_t stream) {
    const int*   center_id = (const int*)  d_in[0];
    const int*   pos_id    = (const int*)  d_in[1];
    const int*   neg_ids   = (const int*)  d_in[2];
    const float* W_in      = (const float*)d_in[3];
    const float* W_out     = (const float*)d_in[4];
    float*       out       = (float*)d_out;
    float*       partial   = (float*)d_ws;       // 2048 floats = 8 KB of workspace

    skipgram_partial_kernel<<<GRID, 256, 0, stream>>>(
        center_id, pos_id, neg_ids, W_in, W_out, partial);
    skipgram_reduce_kernel<<<1, 256, 0, stream>>>(partial, out);
}